// Round 7
// baseline (1106.121 us; speedup 1.0000x reference)
//
#include <hip/hip_runtime.h>
#include <math.h>

#define N_NODES 50000
#define N_EDGES 400000
#define CH      256
#define NNZ     800000

typedef short s16x8 __attribute__((ext_vector_type(8)));
typedef float f32x4 __attribute__((ext_vector_type(4)));

__device__ __forceinline__ float sigmoidf_(float x) {
    return 1.0f / (1.0f + __expf(-x));
}
__device__ __forceinline__ unsigned short f2bf(float f) {
    unsigned u = __float_as_uint(f);
    u = (u + 0x7FFFu + ((u >> 16) & 1u)) >> 16;   // RNE
    return (unsigned short)u;
}
__device__ __forceinline__ float bf2f(unsigned short h) {
    return __uint_as_float((unsigned)h << 16);
}

// ---------------------------------------------------------------------------
__global__ __launch_bounds__(256) void fill_i32(int* __restrict__ p, int val, int n)
{
    int stride = gridDim.x * 256;
    for (int i = blockIdx.x * 256 + threadIdx.x; i < n; i += stride) p[i] = val;
}

__global__ __launch_bounds__(256) void build_list(
    const int* __restrict__ key, int* __restrict__ head, int* __restrict__ nxt, int n)
{
    int i = blockIdx.x * 256 + threadIdx.x;
    if (i >= n) return;
    nxt[i] = atomicExch(&head[key[i]], i);
}

// Linked list -> packed CSR (no scan): sd[k] = base | (deg<<20).
__global__ __launch_bounds__(256) void pack_csr(
    const int* __restrict__ head, const int* __restrict__ nxt,
    const int* __restrict__ other, const float* __restrict__ vals_src,
    int* __restrict__ sd, int* __restrict__ col_out, float* __restrict__ val_out,
    int* __restrict__ cursor, int n_keys)
{
    int k = blockIdx.x * 256 + threadIdx.x;
    if (k >= n_keys) return;
    int deg = 0;
    for (int p = head[k]; p >= 0; p = nxt[p]) deg++;
    int base = deg ? atomicAdd(cursor, deg) : 0;
    sd[k] = base | (deg << 20);
    int i = base;
    for (int p = head[k]; p >= 0; p = nxt[p]) {
        col_out[i] = other[p];
        val_out[i] = vals_src[p];
        i++;
    }
}

// W[k][n] fp32 -> Wt[n][k] bf16 (transposed; MFMA B-frags contiguous)
__global__ __launch_bounds__(256) void cvt_w_transpose(
    const float* __restrict__ W0, const float* __restrict__ W1,
    unsigned short* __restrict__ T0, unsigned short* __restrict__ T1)
{
    int n = blockIdx.x, k = threadIdx.x;
    T0[n * 256 + k] = f2bf(W0[k * 256 + n]);
    T1[n * 256 + k] = f2bf(W1[k * 256 + n]);
}

// W[k][n] fp32 -> hi/lo bf16 in FRAG-PACKED layout for final_mfma LDS staging:
//   out[((k0i*4 + g)*256 + n)*8 + j]  where k = k0i*32 + g*8 + j
__global__ __launch_bounds__(256) void cvt_w_hilo_pk(
    const float* __restrict__ W,
    unsigned short* __restrict__ Th, unsigned short* __restrict__ Tl)
{
    int n = blockIdx.x, k = threadIdx.x;
    float w = W[k * 256 + n];
    unsigned short h = f2bf(w);
    int k0i = k >> 5, g = (k >> 3) & 3, j = k & 7;
    size_t o = (((size_t)(k0i * 4 + g)) * 256 + n) * 8 + j;
    Th[o] = h;
    Tl[o] = f2bf(w - bf2f(h));
}

// ---------------------------------------------------------------------------
// MFMA GEMM: Y[M][256] (bf16) = X[M][256] (fp32) @ W (via Wt[n][k] bf16)
// ---------------------------------------------------------------------------
__global__ __launch_bounds__(256) void mfma_gemm(
    const float* __restrict__ X, const unsigned short* __restrict__ Wt,
    unsigned short* __restrict__ Y, int M)
{
    const int wv = threadIdx.x >> 6, lane = threadIdx.x & 63;
    const int row0 = blockIdx.x * 64 + wv * 16;
    const int r = lane & 15, g = lane >> 4;

    f32x4 acc[16];
#pragma unroll
    for (int t = 0; t < 16; t++) acc[t] = (f32x4){0.f, 0.f, 0.f, 0.f};

    int arow = row0 + r; if (arow >= M) arow = M - 1;

#pragma unroll
    for (int k0 = 0; k0 < 256; k0 += 32) {
        const float* xp = X + (size_t)arow * CH + k0 + g * 8;
        float4 f0 = *(const float4*)(xp);
        float4 f1 = *(const float4*)(xp + 4);
        s16x8 a;
        a[0] = f2bf(f0.x); a[1] = f2bf(f0.y); a[2] = f2bf(f0.z); a[3] = f2bf(f0.w);
        a[4] = f2bf(f1.x); a[5] = f2bf(f1.y); a[6] = f2bf(f1.z); a[7] = f2bf(f1.w);
#pragma unroll
        for (int t = 0; t < 16; t++) {
            s16x8 b = *(const s16x8*)(Wt + (size_t)(t * 16 + r) * CH + k0 + g * 8);
            acc[t] = __builtin_amdgcn_mfma_f32_16x16x32_bf16(a, b, acc[t], 0, 0, 0);
        }
    }

    const int drow0 = row0 + g * 4;
#pragma unroll
    for (int t = 0; t < 16; t++) {
        int col = t * 16 + r;
#pragma unroll
        for (int j = 0; j < 4; j++) {
            int dr = drow0 + j;
            if (dr < M) Y[(size_t)dr * CH + col] = f2bf(acc[t][j]);
        }
    }
}

// ---------------------------------------------------------------------------
// CSR gather SpMM (bf16 rows): O[r] = act( sum_i val[i]*S[col[i]] ), unroll x8
// ---------------------------------------------------------------------------
__global__ __launch_bounds__(256) void gather_csr(
    const int* __restrict__ sd, const int* __restrict__ col,
    const float* __restrict__ val, const unsigned short* __restrict__ S,
    void* __restrict__ O, int n_rows, int sig, int out_bf)
{
    int r    = (int)((blockIdx.x * 256u + threadIdx.x) >> 6);
    int lane = threadIdx.x & 63;
    if (r >= n_rows) return;
    r = __builtin_amdgcn_readfirstlane(r);

    unsigned sdv = (unsigned)sd[r];
    int base = (int)(sdv & 0xFFFFFu), deg = (int)(sdv >> 20);
    const int lo = lane * 4;

    float4 acc = make_float4(0.f, 0.f, 0.f, 0.f);
    int i = 0;
    for (; i + 8 <= deg; i += 8) {
        int   c[8]; float v[8]; ushort4 s[8];
#pragma unroll
        for (int q = 0; q < 8; q++) { c[q] = col[base+i+q]; v[q] = val[base+i+q]; }
#pragma unroll
        for (int q = 0; q < 8; q++) s[q] = *(const ushort4*)(S + (size_t)c[q] * CH + lo);
#pragma unroll
        for (int q = 0; q < 8; q++) {
            acc.x = fmaf(v[q], bf2f(s[q].x), acc.x);
            acc.y = fmaf(v[q], bf2f(s[q].y), acc.y);
            acc.z = fmaf(v[q], bf2f(s[q].z), acc.z);
            acc.w = fmaf(v[q], bf2f(s[q].w), acc.w);
        }
    }
    for (; i + 4 <= deg; i += 4) {
        int   c[4]; float v[4]; ushort4 s[4];
#pragma unroll
        for (int q = 0; q < 4; q++) { c[q] = col[base+i+q]; v[q] = val[base+i+q]; }
#pragma unroll
        for (int q = 0; q < 4; q++) s[q] = *(const ushort4*)(S + (size_t)c[q] * CH + lo);
#pragma unroll
        for (int q = 0; q < 4; q++) {
            acc.x = fmaf(v[q], bf2f(s[q].x), acc.x);
            acc.y = fmaf(v[q], bf2f(s[q].y), acc.y);
            acc.z = fmaf(v[q], bf2f(s[q].z), acc.z);
            acc.w = fmaf(v[q], bf2f(s[q].w), acc.w);
        }
    }
    for (; i < deg; i++) {
        int   c = col[base+i];
        float v = val[base+i];
        ushort4 s = *(const ushort4*)(S + (size_t)c * CH + lo);
        acc.x = fmaf(v, bf2f(s.x), acc.x);
        acc.y = fmaf(v, bf2f(s.y), acc.y);
        acc.z = fmaf(v, bf2f(s.z), acc.z);
        acc.w = fmaf(v, bf2f(s.w), acc.w);
    }
    if (sig) {
        acc.x = sigmoidf_(acc.x); acc.y = sigmoidf_(acc.y);
        acc.z = sigmoidf_(acc.z); acc.w = sigmoidf_(acc.w);
    }
    if (out_bf) {
        ushort4 o; o.x = f2bf(acc.x); o.y = f2bf(acc.y); o.z = f2bf(acc.z); o.w = f2bf(acc.w);
        *(ushort4*)((unsigned short*)O + (size_t)r * CH + lo) = o;
    } else {
        *(float4*)((float*)O + (size_t)r * CH + lo) = acc;
    }
}

// ---------------------------------------------------------------------------
// Edge branch via double CSR. Key structural fact: every edge e in node n's
// incidence list CONTAINS n, so one member row per segment is B[n] itself —
// cache it in registers (saves 800k of 2.4M row reads; deg-1 edges load-free).
// Also prefetch next segment's sd_e to break the dependence chain.
// ---------------------------------------------------------------------------
__global__ __launch_bounds__(256) void edge_gather_csr(
    const int* __restrict__ sd_n, const int* __restrict__ edge_n,
    const float* __restrict__ val_n,
    const int* __restrict__ sd_e, const int* __restrict__ node_e,
    const float* __restrict__ val_e,
    const unsigned short* __restrict__ B, float* __restrict__ F, int n_nodes)
{
    int n    = (int)((blockIdx.x * 256u + threadIdx.x) >> 6);
    int lane = threadIdx.x & 63;
    if (n >= n_nodes) return;
    n = __builtin_amdgcn_readfirstlane(n);

    unsigned sdn = (unsigned)sd_n[n];
    int baseN = (int)(sdn & 0xFFFFFu), degN = (int)(sdn >> 20);
    const int lo = lane * 4;

    ushort4 bo = *(const ushort4*)(B + (size_t)n * CH + lo);
    float4 b_own = make_float4(bf2f(bo.x), bf2f(bo.y), bf2f(bo.z), bf2f(bo.w));

    float4 acc = make_float4(0.f, 0.f, 0.f, 0.f);
    unsigned sde_nxt = 0;
    if (degN > 0) sde_nxt = (unsigned)sd_e[edge_n[baseN]];

    for (int i = 0; i < degN; i++) {
        float v = val_n[baseN + i];
        unsigned sde = sde_nxt;
        if (i + 1 < degN) sde_nxt = (unsigned)sd_e[edge_n[baseN + i + 1]];
        int baseE = (int)(sde & 0xFFFFFu), degE = (int)(sde >> 20);

        float4 d = make_float4(0.f, 0.f, 0.f, 0.f);
        for (int j = 0; j < degE; j++) {
            int   m = node_e[baseE + j];
            float u = val_e[baseE + j];
            if (m == n) {   // wave-uniform branch: scalar skip, no divergence
                d.x = fmaf(u, b_own.x, d.x);
                d.y = fmaf(u, b_own.y, d.y);
                d.z = fmaf(u, b_own.z, d.z);
                d.w = fmaf(u, b_own.w, d.w);
            } else {
                ushort4 b = *(const ushort4*)(B + (size_t)m * CH + lo);
                d.x = fmaf(u, bf2f(b.x), d.x);
                d.y = fmaf(u, bf2f(b.y), d.y);
                d.z = fmaf(u, bf2f(b.z), d.z);
                d.w = fmaf(u, bf2f(b.w), d.w);
            }
        }
        acc.x = fmaf(v, sigmoidf_(d.x), acc.x);
        acc.y = fmaf(v, sigmoidf_(d.y), acc.y);
        acc.z = fmaf(v, sigmoidf_(d.z), acc.z);
        acc.w = fmaf(v, sigmoidf_(d.w), acc.w);
    }
    *(float4*)(F + (size_t)n * CH + lo) = acc;
}

// ---------------------------------------------------------------------------
// Final GEMM, split-bf16 MFMA, fp32-equivalent, weight-stationary via LDS:
//   out = sigmoid( E@W10 + F@W11 ),  E fp32 (in d_out, in-place safe), F fp32.
// Per k0-slice: stage 4 x 16KB frag-packed W slices into LDS once per block
// (shared by 4 waves), then 16 t-tiles x 12 MFMA. 257-frag stride = bank-balanced.
// ---------------------------------------------------------------------------
__device__ __forceinline__ void split8(float4 a, float4 b, s16x8& hi, s16x8& lo)
{
    float v[8] = {a.x, a.y, a.z, a.w, b.x, b.y, b.z, b.w};
#pragma unroll
    for (int i = 0; i < 8; i++) {
        unsigned short h = f2bf(v[i]);
        hi[i] = (short)h;
        lo[i] = (short)f2bf(v[i] - bf2f(h));
    }
}

__global__ __launch_bounds__(256) void final_mfma(
    const float* __restrict__ E, const float* __restrict__ F,
    const unsigned short* __restrict__ Wh10, const unsigned short* __restrict__ Wl10,
    const unsigned short* __restrict__ Wh11, const unsigned short* __restrict__ Wl11,
    float* __restrict__ Y, int M)
{
    __shared__ unsigned short lds[4 * 4 * 257 * 8];   // 65792 B
    const int tid = threadIdx.x;
    const int wv = tid >> 6, lane = tid & 63;
    const int row0 = blockIdx.x * 128 + wv * 32;
    const int r = lane & 15, g = lane >> 4;

    f32x4 acc[2][16];
#pragma unroll
    for (int gr = 0; gr < 2; gr++)
#pragma unroll
        for (int t = 0; t < 16; t++) acc[gr][t] = (f32x4){0.f, 0.f, 0.f, 0.f};

    int ar0 = row0 + r;      if (ar0 >= M) ar0 = M - 1;
    int ar1 = row0 + 16 + r; if (ar1 >= M) ar1 = M - 1;

    for (int k0i = 0; k0i < 8; ++k0i) {
        const int kbase = k0i * 32 + g * 8;
        // issue E/F global loads early (overlap LDS staging)
        const float* p = E + (size_t)ar0 * CH + kbase;
        float4 e0a = *(const float4*)p, e0b = *(const float4*)(p + 4);
        p = E + (size_t)ar1 * CH + kbase;
        float4 e1a = *(const float4*)p, e1b = *(const float4*)(p + 4);
        p = F + (size_t)ar0 * CH + kbase;
        float4 f0a = *(const float4*)p, f0b = *(const float4*)(p + 4);
        p = F + (size_t)ar1 * CH + kbase;
        float4 f1a = *(const float4*)p, f1b = *(const float4*)(p + 4);

        if (k0i) __syncthreads();   // previous slice's reads complete
#pragma unroll
        for (int m = 0; m < 4; m++) {
            const unsigned short* src =
                (m == 0) ? Wh10 : (m == 1) ? Wl10 : (m == 2) ? Wh11 : Wl11;
            src += (size_t)k0i * 1024 * 8;
#pragma unroll
            for (int g2 = 0; g2 < 4; g2++) {
                int frag = (m * 4 + g2) * 257 + tid;
                *(s16x8*)&lds[frag * 8] = *(const s16x8*)(src + (size_t)(g2 * 256 + tid) * 8);
            }
        }
        __syncthreads();

        s16x8 eh0, el0, eh1, el1, fh0, fl0, fh1, fl1;
        split8(e0a, e0b, eh0, el0);
        split8(e1a, e1b, eh1, el1);
        split8(f0a, f0b, fh0, fl0);
        split8(f1a, f1b, fh1, fl1);

#pragma unroll 4
        for (int t = 0; t < 16; t++) {
            int rr = t * 16 + r;
            s16x8 bh0 = *(const s16x8*)&lds[((0 + g) * 257 + rr) * 8];
            s16x8 bl0 = *(const s16x8*)&lds[((4 + g) * 257 + rr) * 8];
            s16x8 bh1 = *(const s16x8*)&lds[((8 + g) * 257 + rr) * 8];
            s16x8 bl1 = *(const s16x8*)&lds[((12 + g) * 257 + rr) * 8];

            acc[0][t] = __builtin_amdgcn_mfma_f32_16x16x32_bf16(eh0, bh0, acc[0][t], 0, 0, 0);
            acc[0][t] = __builtin_amdgcn_mfma_f32_16x16x32_bf16(el0, bh0, acc[0][t], 0, 0, 0);
            acc[0][t] = __builtin_amdgcn_mfma_f32_16x16x32_bf16(eh0, bl0, acc[0][t], 0, 0, 0);
            acc[0][t] = __builtin_amdgcn_mfma_f32_16x16x32_bf16(fh0, bh1, acc[0][t], 0, 0, 0);
            acc[0][t] = __builtin_amdgcn_mfma_f32_16x16x32_bf16(fl0, bh1, acc[0][t], 0, 0, 0);
            acc[0][t] = __builtin_amdgcn_mfma_f32_16x16x32_bf16(fh0, bl1, acc[0][t], 0, 0, 0);

            acc[1][t] = __builtin_amdgcn_mfma_f32_16x16x32_bf16(eh1, bh0, acc[1][t], 0, 0, 0);
            acc[1][t] = __builtin_amdgcn_mfma_f32_16x16x32_bf16(el1, bh0, acc[1][t], 0, 0, 0);
            acc[1][t] = __builtin_amdgcn_mfma_f32_16x16x32_bf16(eh1, bl0, acc[1][t], 0, 0, 0);
            acc[1][t] = __builtin_amdgcn_mfma_f32_16x16x32_bf16(fh1, bh1, acc[1][t], 0, 0, 0);
            acc[1][t] = __builtin_amdgcn_mfma_f32_16x16x32_bf16(fl1, bh1, acc[1][t], 0, 0, 0);
            acc[1][t] = __builtin_amdgcn_mfma_f32_16x16x32_bf16(fh1, bl1, acc[1][t], 0, 0, 0);
        }
    }

#pragma unroll
    for (int gr = 0; gr < 2; gr++) {
        const int drow0 = row0 + gr * 16 + g * 4;
#pragma unroll
        for (int t = 0; t < 16; t++) {
            int col = t * 16 + r;
#pragma unroll
            for (int j = 0; j < 4; j++) {
                int dr = drow0 + j;
                if (dr < M) Y[(size_t)dr * CH + col] = sigmoidf_(acc[gr][t][j]);
            }
        }
    }
}

// ---------------------------------------------------------------------------
extern "C" void kernel_launch(void* const* d_in, const int* in_sizes, int n_in,
                              void* d_out, int out_size, void* d_ws, size_t ws_size,
                              hipStream_t stream)
{
    const float* x        = (const float*)d_in[0];
    const int*   adj_rows = (const int*)  d_in[1];
    const int*   adj_cols = (const int*)  d_in[2];
    const float* adj_vals = (const float*)d_in[3];
    const int*   inc_rows = (const int*)  d_in[4];
    const int*   inc_cols = (const int*)  d_in[5];
    const float* inc_vals = (const float*)d_in[6];
    const float* W00      = (const float*)d_in[7];
    const float* W01      = (const float*)d_in[8];
    const float* W10      = (const float*)d_in[9];
    const float* W11      = (const float*)d_in[10];

    // -------- workspace layout (110.4 MB total; proven-safe < 114.26 MB) ----
    const size_t SZ_AB = (size_t)N_NODES * CH * 2;    // 25.6 MB
    const size_t SZ_F  = (size_t)N_NODES * CH * 4;    // 51.2 MB
    char* ws = (char*)d_ws;
    size_t off = 0;
    unsigned short* AB_bf = (unsigned short*)(ws + off); off += SZ_AB;
    float*          F     = (float*)(ws + off);          off += SZ_F;
    int*   sd_a  = (int*)(ws + off);  off += (size_t)N_NODES * 4;
    int*   col_a = (int*)(ws + off);  off += (size_t)NNZ * 4;
    float* val_a = (float*)(ws + off); off += (size_t)NNZ * 4;
    int*   cursors = (int*)(ws + off); off += 256;
    unsigned short* Wt00  = (unsigned short*)(ws + off); off += (size_t)CH * CH * 2;
    unsigned short* Wt01  = (unsigned short*)(ws + off); off += (size_t)CH * CH * 2;
    unsigned short* Wh10  = (unsigned short*)(ws + off); off += (size_t)CH * CH * 2;
    unsigned short* Wl10  = (unsigned short*)(ws + off); off += (size_t)CH * CH * 2;
    unsigned short* Wh11  = (unsigned short*)(ws + off); off += (size_t)CH * CH * 2;
    unsigned short* Wl11  = (unsigned short*)(ws + off); off += (size_t)CH * CH * 2;
    // scratch: lists + inc CSRs (dead after edge_gather_csr); C_bf overlays it
    char* scratch = ws + off;
    int*   head_a = (int*)(scratch);
    int*   head_e = head_a + N_NODES;
    int*   head_n = head_e + N_EDGES;
    int*   nxt_a  = head_n + N_NODES;
    int*   nxt_e  = nxt_a + NNZ;
    int*   nxt_n  = nxt_e + NNZ;
    int*   sd_n   = nxt_n + NNZ;
    int*   edge_n = sd_n + N_NODES;
    float* val_n  = (float*)(edge_n + NNZ);
    int*   sd_e   = (int*)(val_n + NNZ);
    int*   node_e = sd_e + N_EDGES;
    float* val_e  = (float*)(node_e + NNZ);
    unsigned short* C_bf = (unsigned short*)scratch;
    float* E = (float*)d_out;

    const int gemm_blocks  = (N_NODES + 63) / 64;          // 782
    const int final_blocks = (N_NODES + 127) / 128;        // 391
    const int row_blocks   = (N_NODES * 64 + 255) / 256;   // 12500
    const int list_blocks  = (NNZ + 255) / 256;

    // 0) lists -> CSR + weight transposes (frag-packed hi/lo for W10/W11)
    fill_i32<<<1024, 256, 0, stream>>>(head_a, -1, N_NODES + N_EDGES + N_NODES);
    fill_i32<<<1, 64, 0, stream>>>(cursors, 0, 3);
    build_list<<<list_blocks, 256, 0, stream>>>(adj_rows, head_a, nxt_a, NNZ);
    build_list<<<list_blocks, 256, 0, stream>>>(inc_cols, head_e, nxt_e, NNZ);
    build_list<<<list_blocks, 256, 0, stream>>>(inc_rows, head_n, nxt_n, NNZ);
    pack_csr<<<(N_NODES + 255) / 256, 256, 0, stream>>>(
        head_a, nxt_a, adj_cols, adj_vals, sd_a, col_a, val_a, cursors + 0, N_NODES);
    pack_csr<<<(N_EDGES + 255) / 256, 256, 0, stream>>>(
        head_e, nxt_e, inc_rows, inc_vals, sd_e, node_e, val_e, cursors + 1, N_EDGES);
    pack_csr<<<(N_NODES + 255) / 256, 256, 0, stream>>>(
        head_n, nxt_n, inc_cols, inc_vals, sd_n, edge_n, val_n, cursors + 2, N_NODES);
    cvt_w_transpose<<<256, 256, 0, stream>>>(W00, W01, Wt00, Wt01);
    cvt_w_hilo_pk<<<256, 256, 0, stream>>>(W10, Wh10, Wl10);
    cvt_w_hilo_pk<<<256, 256, 0, stream>>>(W11, Wh11, Wl11);

    // 1) B = x @ W01  (bf16, MFMA)
    mfma_gemm<<<gemm_blocks, 256, 0, stream>>>(x, Wt01, AB_bf, N_NODES);

    // 2) F[n] = sum v * sigmoid(D_e)  (double-CSR, own-row cached, registers only)
    edge_gather_csr<<<row_blocks, 256, 0, stream>>>(sd_n, edge_n, val_n,
                                                    sd_e, node_e, val_e,
                                                    AB_bf, F, N_NODES);

    // 3) A = x @ W00  (overwrites B — dead)
    mfma_gemm<<<gemm_blocks, 256, 0, stream>>>(x, Wt00, AB_bf, N_NODES);

    // 4) C = sigmoid(gather_adj(A)) -> bf16  (overlays dead scratch)
    gather_csr<<<row_blocks, 256, 0, stream>>>(sd_a, col_a, val_a,
                                               AB_bf, C_bf, N_NODES, 1, 1);

    // 5) E = gather_adj(C) -> fp32 in d_out
    gather_csr<<<row_blocks, 256, 0, stream>>>(sd_a, col_a, val_a,
                                               C_bf, E, N_NODES, 0, 0);

    // 6) out = sigmoid(E @ W10 + F @ W11)  (split-bf16 MFMA, LDS weight-stationary,
    //    in-place on d_out: each block reads only its own rows pre-write)
    final_mfma<<<final_blocks, 256, 0, stream>>>(E, F, Wh10, Wl10, Wh11, Wl11,
                                                 (float*)d_out, N_NODES);
}

// Round 8
// 1105.564 us; speedup vs baseline: 1.0005x; 1.0005x over previous
//
#include <hip/hip_runtime.h>
#include <math.h>

#define N_NODES 50000
#define N_EDGES 400000
#define CH      256
#define NNZ     800000

typedef short s16x8 __attribute__((ext_vector_type(8)));
typedef float f32x4 __attribute__((ext_vector_type(4)));

__device__ __forceinline__ float sigmoidf_(float x) {
    return 1.0f / (1.0f + __expf(-x));
}
__device__ __forceinline__ unsigned short f2bf(float f) {
    unsigned u = __float_as_uint(f);
    u = (u + 0x7FFFu + ((u >> 16) & 1u)) >> 16;   // RNE
    return (unsigned short)u;
}
__device__ __forceinline__ float bf2f(unsigned short h) {
    return __uint_as_float((unsigned)h << 16);
}

// ---------------------------------------------------------------------------
__global__ __launch_bounds__(256) void fill_i32(int* __restrict__ p, int val, int n)
{
    int stride = gridDim.x * 256;
    for (int i = blockIdx.x * 256 + threadIdx.x; i < n; i += stride) p[i] = val;
}

__global__ __launch_bounds__(256) void build_list(
    const int* __restrict__ key, int* __restrict__ head, int* __restrict__ nxt, int n)
{
    int i = blockIdx.x * 256 + threadIdx.x;
    if (i >= n) return;
    nxt[i] = atomicExch(&head[key[i]], i);
}

// Linked list -> packed CSR (no scan): sd[k] = base | (deg<<20).
__global__ __launch_bounds__(256) void pack_csr(
    const int* __restrict__ head, const int* __restrict__ nxt,
    const int* __restrict__ other, const float* __restrict__ vals_src,
    int* __restrict__ sd, int* __restrict__ col_out, float* __restrict__ val_out,
    int* __restrict__ cursor, int n_keys)
{
    int k = blockIdx.x * 256 + threadIdx.x;
    if (k >= n_keys) return;
    int deg = 0;
    for (int p = head[k]; p >= 0; p = nxt[p]) deg++;
    int base = deg ? atomicAdd(cursor, deg) : 0;
    sd[k] = base | (deg << 20);
    int i = base;
    for (int p = head[k]; p >= 0; p = nxt[p]) {
        col_out[i] = other[p];
        val_out[i] = vals_src[p];
        i++;
    }
}

// W[k][n] fp32 -> Wt[n][k] bf16 (transposed; MFMA B-frags contiguous)
__global__ __launch_bounds__(256) void cvt_w_transpose(
    const float* __restrict__ W0, const float* __restrict__ W1,
    unsigned short* __restrict__ T0, unsigned short* __restrict__ T1)
{
    int n = blockIdx.x, k = threadIdx.x;
    T0[n * 256 + k] = f2bf(W0[k * 256 + n]);
    T1[n * 256 + k] = f2bf(W1[k * 256 + n]);
}

// W[k][n] fp32 -> hi/lo bf16 in FRAG-PACKED layout for final_mfma LDS staging:
//   out[((k0i*4 + g)*256 + n)*8 + j]  where k = k0i*32 + g*8 + j
__global__ __launch_bounds__(256) void cvt_w_hilo_pk(
    const float* __restrict__ W,
    unsigned short* __restrict__ Th, unsigned short* __restrict__ Tl)
{
    int n = blockIdx.x, k = threadIdx.x;
    float w = W[k * 256 + n];
    unsigned short h = f2bf(w);
    int k0i = k >> 5, g = (k >> 3) & 3, j = k & 7;
    size_t o = (((size_t)(k0i * 4 + g)) * 256 + n) * 8 + j;
    Th[o] = h;
    Tl[o] = f2bf(w - bf2f(h));
}

// ---------------------------------------------------------------------------
// MFMA GEMM: Y[M][256] (bf16) = X[M][256] (fp32) @ W (via Wt[n][k] bf16)
// ---------------------------------------------------------------------------
__global__ __launch_bounds__(256) void mfma_gemm(
    const float* __restrict__ X, const unsigned short* __restrict__ Wt,
    unsigned short* __restrict__ Y, int M)
{
    const int wv = threadIdx.x >> 6, lane = threadIdx.x & 63;
    const int row0 = blockIdx.x * 64 + wv * 16;
    const int r = lane & 15, g = lane >> 4;

    f32x4 acc[16];
#pragma unroll
    for (int t = 0; t < 16; t++) acc[t] = (f32x4){0.f, 0.f, 0.f, 0.f};

    int arow = row0 + r; if (arow >= M) arow = M - 1;

#pragma unroll
    for (int k0 = 0; k0 < 256; k0 += 32) {
        const float* xp = X + (size_t)arow * CH + k0 + g * 8;
        float4 f0 = *(const float4*)(xp);
        float4 f1 = *(const float4*)(xp + 4);
        s16x8 a;
        a[0] = f2bf(f0.x); a[1] = f2bf(f0.y); a[2] = f2bf(f0.z); a[3] = f2bf(f0.w);
        a[4] = f2bf(f1.x); a[5] = f2bf(f1.y); a[6] = f2bf(f1.z); a[7] = f2bf(f1.w);
#pragma unroll
        for (int t = 0; t < 16; t++) {
            s16x8 b = *(const s16x8*)(Wt + (size_t)(t * 16 + r) * CH + k0 + g * 8);
            acc[t] = __builtin_amdgcn_mfma_f32_16x16x32_bf16(a, b, acc[t], 0, 0, 0);
        }
    }

    const int drow0 = row0 + g * 4;
#pragma unroll
    for (int t = 0; t < 16; t++) {
        int col = t * 16 + r;
#pragma unroll
        for (int j = 0; j < 4; j++) {
            int dr = drow0 + j;
            if (dr < M) Y[(size_t)dr * CH + col] = f2bf(acc[t][j]);
        }
    }
}

// ---------------------------------------------------------------------------
// CSR gather SpMM (bf16 rows): O[r] = act( sum_i val[i]*S[col[i]] ), unroll x8
// ---------------------------------------------------------------------------
__global__ __launch_bounds__(256) void gather_csr(
    const int* __restrict__ sd, const int* __restrict__ col,
    const float* __restrict__ val, const unsigned short* __restrict__ S,
    void* __restrict__ O, int n_rows, int sig, int out_bf)
{
    int r    = (int)((blockIdx.x * 256u + threadIdx.x) >> 6);
    int lane = threadIdx.x & 63;
    if (r >= n_rows) return;
    r = __builtin_amdgcn_readfirstlane(r);

    unsigned sdv = (unsigned)sd[r];
    int base = (int)(sdv & 0xFFFFFu), deg = (int)(sdv >> 20);
    const int lo = lane * 4;

    float4 acc = make_float4(0.f, 0.f, 0.f, 0.f);
    int i = 0;
    for (; i + 8 <= deg; i += 8) {
        int   c[8]; float v[8]; ushort4 s[8];
#pragma unroll
        for (int q = 0; q < 8; q++) { c[q] = col[base+i+q]; v[q] = val[base+i+q]; }
#pragma unroll
        for (int q = 0; q < 8; q++) s[q] = *(const ushort4*)(S + (size_t)c[q] * CH + lo);
#pragma unroll
        for (int q = 0; q < 8; q++) {
            acc.x = fmaf(v[q], bf2f(s[q].x), acc.x);
            acc.y = fmaf(v[q], bf2f(s[q].y), acc.y);
            acc.z = fmaf(v[q], bf2f(s[q].z), acc.z);
            acc.w = fmaf(v[q], bf2f(s[q].w), acc.w);
        }
    }
    for (; i + 4 <= deg; i += 4) {
        int   c[4]; float v[4]; ushort4 s[4];
#pragma unroll
        for (int q = 0; q < 4; q++) { c[q] = col[base+i+q]; v[q] = val[base+i+q]; }
#pragma unroll
        for (int q = 0; q < 4; q++) s[q] = *(const ushort4*)(S + (size_t)c[q] * CH + lo);
#pragma unroll
        for (int q = 0; q < 4; q++) {
            acc.x = fmaf(v[q], bf2f(s[q].x), acc.x);
            acc.y = fmaf(v[q], bf2f(s[q].y), acc.y);
            acc.z = fmaf(v[q], bf2f(s[q].z), acc.z);
            acc.w = fmaf(v[q], bf2f(s[q].w), acc.w);
        }
    }
    for (; i < deg; i++) {
        int   c = col[base+i];
        float v = val[base+i];
        ushort4 s = *(const ushort4*)(S + (size_t)c * CH + lo);
        acc.x = fmaf(v, bf2f(s.x), acc.x);
        acc.y = fmaf(v, bf2f(s.y), acc.y);
        acc.z = fmaf(v, bf2f(s.z), acc.z);
        acc.w = fmaf(v, bf2f(s.w), acc.w);
    }
    if (sig) {
        acc.x = sigmoidf_(acc.x); acc.y = sigmoidf_(acc.y);
        acc.z = sigmoidf_(acc.z); acc.w = sigmoidf_(acc.w);
    }
    if (out_bf) {
        ushort4 o; o.x = f2bf(acc.x); o.y = f2bf(acc.y); o.z = f2bf(acc.z); o.w = f2bf(acc.w);
        *(ushort4*)((unsigned short*)O + (size_t)r * CH + lo) = o;
    } else {
        *(float4*)((float*)O + (size_t)r * CH + lo) = acc;
    }
}

// ---------------------------------------------------------------------------
// Edge branch via double CSR (R6 form — own-row caching was refuted by FETCH
// counters: those reads were already cache hits; the branch+prefetch cost 5%)
// ---------------------------------------------------------------------------
__global__ __launch_bounds__(256) void edge_gather_csr(
    const int* __restrict__ sd_n, const int* __restrict__ edge_n,
    const float* __restrict__ val_n,
    const int* __restrict__ sd_e, const int* __restrict__ node_e,
    const float* __restrict__ val_e,
    const unsigned short* __restrict__ B, float* __restrict__ F, int n_nodes)
{
    int n    = (int)((blockIdx.x * 256u + threadIdx.x) >> 6);
    int lane = threadIdx.x & 63;
    if (n >= n_nodes) return;
    n = __builtin_amdgcn_readfirstlane(n);

    unsigned sdn = (unsigned)sd_n[n];
    int baseN = (int)(sdn & 0xFFFFFu), degN = (int)(sdn >> 20);
    const int lo = lane * 4;

    float4 acc = make_float4(0.f, 0.f, 0.f, 0.f);
    for (int i = 0; i < degN; i++) {
        int   e = edge_n[baseN + i];
        float v = val_n[baseN + i];
        unsigned sde = (unsigned)sd_e[e];
        int baseE = (int)(sde & 0xFFFFFu), degE = (int)(sde >> 20);

        float4 d = make_float4(0.f, 0.f, 0.f, 0.f);
        int j = 0;
        for (; j + 2 <= degE; j += 2) {
            int   m0 = node_e[baseE+j],   m1 = node_e[baseE+j+1];
            float u0 = val_e[baseE+j],    u1 = val_e[baseE+j+1];
            ushort4 b0 = *(const ushort4*)(B + (size_t)m0 * CH + lo);
            ushort4 b1 = *(const ushort4*)(B + (size_t)m1 * CH + lo);
            d.x += u0*bf2f(b0.x) + u1*bf2f(b1.x);
            d.y += u0*bf2f(b0.y) + u1*bf2f(b1.y);
            d.z += u0*bf2f(b0.z) + u1*bf2f(b1.z);
            d.w += u0*bf2f(b0.w) + u1*bf2f(b1.w);
        }
        for (; j < degE; j++) {
            int   m = node_e[baseE+j];
            float u = val_e[baseE+j];
            ushort4 b = *(const ushort4*)(B + (size_t)m * CH + lo);
            d.x = fmaf(u, bf2f(b.x), d.x);
            d.y = fmaf(u, bf2f(b.y), d.y);
            d.z = fmaf(u, bf2f(b.z), d.z);
            d.w = fmaf(u, bf2f(b.w), d.w);
        }
        acc.x = fmaf(v, sigmoidf_(d.x), acc.x);
        acc.y = fmaf(v, sigmoidf_(d.y), acc.y);
        acc.z = fmaf(v, sigmoidf_(d.z), acc.z);
        acc.w = fmaf(v, sigmoidf_(d.w), acc.w);
    }
    *(float4*)(F + (size_t)n * CH + lo) = acc;
}

// ---------------------------------------------------------------------------
// Final GEMM, split-bf16 MFMA, fp32-equivalent, weight-stationary via LDS.
// __launch_bounds__(256, 2): min 2 waves/EU -> 256-VGPR budget. R7's version
// spilled acc to scratch (VGPR_Count=88, WRITE_SIZE 498MB) under the default
// occupancy heuristic — this was the whole regression.
// ---------------------------------------------------------------------------
__device__ __forceinline__ void split8(float4 a, float4 b, s16x8& hi, s16x8& lo)
{
    float v[8] = {a.x, a.y, a.z, a.w, b.x, b.y, b.z, b.w};
#pragma unroll
    for (int i = 0; i < 8; i++) {
        unsigned short h = f2bf(v[i]);
        hi[i] = (short)h;
        lo[i] = (short)f2bf(v[i] - bf2f(h));
    }
}

__global__ __launch_bounds__(256, 2) void final_mfma(
    const float* __restrict__ E, const float* __restrict__ F,
    const unsigned short* __restrict__ Wh10, const unsigned short* __restrict__ Wl10,
    const unsigned short* __restrict__ Wh11, const unsigned short* __restrict__ Wl11,
    float* __restrict__ Y, int M)
{
    __shared__ unsigned short lds[4 * 4 * 257 * 8];   // 65792 B (2 blocks/CU)
    const int tid = threadIdx.x;
    const int wv = tid >> 6, lane = tid & 63;
    const int row0 = blockIdx.x * 128 + wv * 32;
    const int r = lane & 15, g = lane >> 4;

    f32x4 acc[2][16];
#pragma unroll
    for (int gr = 0; gr < 2; gr++)
#pragma unroll
        for (int t = 0; t < 16; t++) acc[gr][t] = (f32x4){0.f, 0.f, 0.f, 0.f};

    int ar0 = row0 + r;      if (ar0 >= M) ar0 = M - 1;
    int ar1 = row0 + 16 + r; if (ar1 >= M) ar1 = M - 1;

    for (int k0i = 0; k0i < 8; ++k0i) {
        const int kbase = k0i * 32 + g * 8;
        // issue E/F global loads early (overlap LDS staging)
        const float* p = E + (size_t)ar0 * CH + kbase;
        float4 e0a = *(const float4*)p, e0b = *(const float4*)(p + 4);
        p = E + (size_t)ar1 * CH + kbase;
        float4 e1a = *(const float4*)p, e1b = *(const float4*)(p + 4);
        p = F + (size_t)ar0 * CH + kbase;
        float4 f0a = *(const float4*)p, f0b = *(const float4*)(p + 4);
        p = F + (size_t)ar1 * CH + kbase;
        float4 f1a = *(const float4*)p, f1b = *(const float4*)(p + 4);

        if (k0i) __syncthreads();   // previous slice's LDS reads complete
#pragma unroll
        for (int m = 0; m < 4; m++) {
            const unsigned short* src =
                (m == 0) ? Wh10 : (m == 1) ? Wl10 : (m == 2) ? Wh11 : Wl11;
            src += (size_t)k0i * 1024 * 8;
#pragma unroll
            for (int g2 = 0; g2 < 4; g2++) {
                int frag = (m * 4 + g2) * 257 + tid;
                *(s16x8*)&lds[frag * 8] = *(const s16x8*)(src + (size_t)(g2 * 256 + tid) * 8);
            }
        }
        __syncthreads();

        s16x8 eh0, el0, eh1, el1, fh0, fl0, fh1, fl1;
        split8(e0a, e0b, eh0, el0);
        split8(e1a, e1b, eh1, el1);
        split8(f0a, f0b, fh0, fl0);
        split8(f1a, f1b, fh1, fl1);

#pragma unroll 4
        for (int t = 0; t < 16; t++) {
            int rr = t * 16 + r;
            s16x8 bh0 = *(const s16x8*)&lds[((0 + g) * 257 + rr) * 8];
            s16x8 bl0 = *(const s16x8*)&lds[((4 + g) * 257 + rr) * 8];
            s16x8 bh1 = *(const s16x8*)&lds[((8 + g) * 257 + rr) * 8];
            s16x8 bl1 = *(const s16x8*)&lds[((12 + g) * 257 + rr) * 8];

            acc[0][t] = __builtin_amdgcn_mfma_f32_16x16x32_bf16(eh0, bh0, acc[0][t], 0, 0, 0);
            acc[0][t] = __builtin_amdgcn_mfma_f32_16x16x32_bf16(el0, bh0, acc[0][t], 0, 0, 0);
            acc[0][t] = __builtin_amdgcn_mfma_f32_16x16x32_bf16(eh0, bl0, acc[0][t], 0, 0, 0);
            acc[0][t] = __builtin_amdgcn_mfma_f32_16x16x32_bf16(fh0, bh1, acc[0][t], 0, 0, 0);
            acc[0][t] = __builtin_amdgcn_mfma_f32_16x16x32_bf16(fl0, bh1, acc[0][t], 0, 0, 0);
            acc[0][t] = __builtin_amdgcn_mfma_f32_16x16x32_bf16(fh0, bl1, acc[0][t], 0, 0, 0);

            acc[1][t] = __builtin_amdgcn_mfma_f32_16x16x32_bf16(eh1, bh0, acc[1][t], 0, 0, 0);
            acc[1][t] = __builtin_amdgcn_mfma_f32_16x16x32_bf16(el1, bh0, acc[1][t], 0, 0, 0);
            acc[1][t] = __builtin_amdgcn_mfma_f32_16x16x32_bf16(eh1, bl0, acc[1][t], 0, 0, 0);
            acc[1][t] = __builtin_amdgcn_mfma_f32_16x16x32_bf16(fh1, bh1, acc[1][t], 0, 0, 0);
            acc[1][t] = __builtin_amdgcn_mfma_f32_16x16x32_bf16(fl1, bh1, acc[1][t], 0, 0, 0);
            acc[1][t] = __builtin_amdgcn_mfma_f32_16x16x32_bf16(fh1, bl1, acc[1][t], 0, 0, 0);
        }
    }

#pragma unroll
    for (int gr = 0; gr < 2; gr++) {
        const int drow0 = row0 + gr * 16 + g * 4;
#pragma unroll
        for (int t = 0; t < 16; t++) {
            int col = t * 16 + r;
#pragma unroll
            for (int j = 0; j < 4; j++) {
                int dr = drow0 + j;
                if (dr < M) Y[(size_t)dr * CH + col] = sigmoidf_(acc[gr][t][j]);
            }
        }
    }
}

// ---------------------------------------------------------------------------
extern "C" void kernel_launch(void* const* d_in, const int* in_sizes, int n_in,
                              void* d_out, int out_size, void* d_ws, size_t ws_size,
                              hipStream_t stream)
{
    const float* x        = (const float*)d_in[0];
    const int*   adj_rows = (const int*)  d_in[1];
    const int*   adj_cols = (const int*)  d_in[2];
    const float* adj_vals = (const float*)d_in[3];
    const int*   inc_rows = (const int*)  d_in[4];
    const int*   inc_cols = (const int*)  d_in[5];
    const float* inc_vals = (const float*)d_in[6];
    const float* W00      = (const float*)d_in[7];
    const float* W01      = (const float*)d_in[8];
    const float* W10      = (const float*)d_in[9];
    const float* W11      = (const float*)d_in[10];

    // -------- workspace layout (110.4 MB total; proven-safe < 114.26 MB) ----
    const size_t SZ_AB = (size_t)N_NODES * CH * 2;    // 25.6 MB
    const size_t SZ_F  = (size_t)N_NODES * CH * 4;    // 51.2 MB
    char* ws = (char*)d_ws;
    size_t off = 0;
    unsigned short* AB_bf = (unsigned short*)(ws + off); off += SZ_AB;
    float*          F     = (float*)(ws + off);          off += SZ_F;
    int*   sd_a  = (int*)(ws + off);  off += (size_t)N_NODES * 4;
    int*   col_a = (int*)(ws + off);  off += (size_t)NNZ * 4;
    float* val_a = (float*)(ws + off); off += (size_t)NNZ * 4;
    int*   cursors = (int*)(ws + off); off += 256;
    unsigned short* Wt00  = (unsigned short*)(ws + off); off += (size_t)CH * CH * 2;
    unsigned short* Wt01  = (unsigned short*)(ws + off); off += (size_t)CH * CH * 2;
    unsigned short* Wh10  = (unsigned short*)(ws + off); off += (size_t)CH * CH * 2;
    unsigned short* Wl10  = (unsigned short*)(ws + off); off += (size_t)CH * CH * 2;
    unsigned short* Wh11  = (unsigned short*)(ws + off); off += (size_t)CH * CH * 2;
    unsigned short* Wl11  = (unsigned short*)(ws + off); off += (size_t)CH * CH * 2;
    // scratch: lists + inc CSRs (dead after edge_gather_csr); C_bf overlays it
    char* scratch = ws + off;
    int*   head_a = (int*)(scratch);
    int*   head_e = head_a + N_NODES;
    int*   head_n = head_e + N_EDGES;
    int*   nxt_a  = head_n + N_NODES;
    int*   nxt_e  = nxt_a + NNZ;
    int*   nxt_n  = nxt_e + NNZ;
    int*   sd_n   = nxt_n + NNZ;
    int*   edge_n = sd_n + N_NODES;
    float* val_n  = (float*)(edge_n + NNZ);
    int*   sd_e   = (int*)(val_n + NNZ);
    int*   node_e = sd_e + N_EDGES;
    float* val_e  = (float*)(node_e + NNZ);
    unsigned short* C_bf = (unsigned short*)scratch;
    float* E = (float*)d_out;

    const int gemm_blocks  = (N_NODES + 63) / 64;          // 782
    const int final_blocks = (N_NODES + 127) / 128;        // 391
    const int row_blocks   = (N_NODES * 64 + 255) / 256;   // 12500
    const int list_blocks  = (NNZ + 255) / 256;

    // 0) lists -> CSR + weight transposes (frag-packed hi/lo for W10/W11)
    fill_i32<<<1024, 256, 0, stream>>>(head_a, -1, N_NODES + N_EDGES + N_NODES);
    fill_i32<<<1, 64, 0, stream>>>(cursors, 0, 3);
    build_list<<<list_blocks, 256, 0, stream>>>(adj_rows, head_a, nxt_a, NNZ);
    build_list<<<list_blocks, 256, 0, stream>>>(inc_cols, head_e, nxt_e, NNZ);
    build_list<<<list_blocks, 256, 0, stream>>>(inc_rows, head_n, nxt_n, NNZ);
    pack_csr<<<(N_NODES + 255) / 256, 256, 0, stream>>>(
        head_a, nxt_a, adj_cols, adj_vals, sd_a, col_a, val_a, cursors + 0, N_NODES);
    pack_csr<<<(N_EDGES + 255) / 256, 256, 0, stream>>>(
        head_e, nxt_e, inc_rows, inc_vals, sd_e, node_e, val_e, cursors + 1, N_EDGES);
    pack_csr<<<(N_NODES + 255) / 256, 256, 0, stream>>>(
        head_n, nxt_n, inc_cols, inc_vals, sd_n, edge_n, val_n, cursors + 2, N_NODES);
    cvt_w_transpose<<<256, 256, 0, stream>>>(W00, W01, Wt00, Wt01);
    cvt_w_hilo_pk<<<256, 256, 0, stream>>>(W10, Wh10, Wl10);
    cvt_w_hilo_pk<<<256, 256, 0, stream>>>(W11, Wh11, Wl11);

    // 1) B = x @ W01  (bf16, MFMA)
    mfma_gemm<<<gemm_blocks, 256, 0, stream>>>(x, Wt01, AB_bf, N_NODES);

    // 2) F[n] = sum v * sigmoid(D_e)  (double-CSR, registers only)
    edge_gather_csr<<<row_blocks, 256, 0, stream>>>(sd_n, edge_n, val_n,
                                                    sd_e, node_e, val_e,
                                                    AB_bf, F, N_NODES);

    // 3) A = x @ W00  (overwrites B — dead)
    mfma_gemm<<<gemm_blocks, 256, 0, stream>>>(x, Wt00, AB_bf, N_NODES);

    // 4) C = sigmoid(gather_adj(A)) -> bf16  (overlays dead scratch)
    gather_csr<<<row_blocks, 256, 0, stream>>>(sd_a, col_a, val_a,
                                               AB_bf, C_bf, N_NODES, 1, 1);

    // 5) E = gather_adj(C) -> fp32 in d_out
    gather_csr<<<row_blocks, 256, 0, stream>>>(sd_a, col_a, val_a,
                                               C_bf, E, N_NODES, 0, 0);

    // 6) out = sigmoid(E @ W10 + F @ W11)  (split-bf16 MFMA, LDS weight-stationary,
    //    in-place on d_out: each block reads only its own rows pre-write)
    final_mfma<<<final_blocks, 256, 0, stream>>>(E, F, Wh10, Wl10, Wh11, Wl11,
                                                 (float*)d_out, N_NODES);
}

// Round 9
// 931.798 us; speedup vs baseline: 1.1871x; 1.1865x over previous
//
#include <hip/hip_runtime.h>
#include <math.h>

#define N_NODES 50000
#define N_EDGES 400000
#define CH      256
#define NNZ     800000

typedef short s16x8 __attribute__((ext_vector_type(8)));
typedef float f32x4 __attribute__((ext_vector_type(4)));

__device__ __forceinline__ float sigmoidf_(float x) {
    return 1.0f / (1.0f + __expf(-x));
}
__device__ __forceinline__ unsigned short f2bf(float f) {
    unsigned u = __float_as_uint(f);
    u = (u + 0x7FFFu + ((u >> 16) & 1u)) >> 16;   // RNE
    return (unsigned short)u;
}
__device__ __forceinline__ float bf2f(unsigned short h) {
    return __uint_as_float((unsigned)h << 16);
}

// ---------------------------------------------------------------------------
__global__ __launch_bounds__(256) void fill_i32(int* __restrict__ p, int val, int n)
{
    int stride = gridDim.x * 256;
    for (int i = blockIdx.x * 256 + threadIdx.x; i < n; i += stride) p[i] = val;
}

__global__ __launch_bounds__(256) void build_list(
    const int* __restrict__ key, int* __restrict__ head, int* __restrict__ nxt, int n)
{
    int i = blockIdx.x * 256 + threadIdx.x;
    if (i >= n) return;
    nxt[i] = atomicExch(&head[key[i]], i);
}

// Linked list -> packed CSR (no scan): sd[k] = base | (deg<<20).
__global__ __launch_bounds__(256) void pack_csr(
    const int* __restrict__ head, const int* __restrict__ nxt,
    const int* __restrict__ other, const float* __restrict__ vals_src,
    int* __restrict__ sd, int* __restrict__ col_out, float* __restrict__ val_out,
    int* __restrict__ cursor, int n_keys)
{
    int k = blockIdx.x * 256 + threadIdx.x;
    if (k >= n_keys) return;
    int deg = 0;
    for (int p = head[k]; p >= 0; p = nxt[p]) deg++;
    int base = deg ? atomicAdd(cursor, deg) : 0;
    sd[k] = base | (deg << 20);
    int i = base;
    for (int p = head[k]; p >= 0; p = nxt[p]) {
        col_out[i] = other[p];
        val_out[i] = vals_src[p];
        i++;
    }
}

// W[k][n] fp32 -> Wt[n][k] bf16 (transposed; MFMA B-frags contiguous)
__global__ __launch_bounds__(256) void cvt_w_transpose(
    const float* __restrict__ W0, const float* __restrict__ W1,
    unsigned short* __restrict__ T0, unsigned short* __restrict__ T1)
{
    int n = blockIdx.x, k = threadIdx.x;
    T0[n * 256 + k] = f2bf(W0[k * 256 + n]);
    T1[n * 256 + k] = f2bf(W1[k * 256 + n]);
}

// W[k][n] fp32 -> hi/lo bf16 in FRAG-PACKED layout for final_mfma LDS staging:
//   out[((k0i*4 + g)*256 + n)*8 + j]  where k = k0i*32 + g*8 + j
__global__ __launch_bounds__(256) void cvt_w_hilo_pk(
    const float* __restrict__ W,
    unsigned short* __restrict__ Th, unsigned short* __restrict__ Tl)
{
    int n = blockIdx.x, k = threadIdx.x;
    float w = W[k * 256 + n];
    unsigned short h = f2bf(w);
    int k0i = k >> 5, g = (k >> 3) & 3, j = k & 7;
    size_t o = (((size_t)(k0i * 4 + g)) * 256 + n) * 8 + j;
    Th[o] = h;
    Tl[o] = f2bf(w - bf2f(h));
}

// ---------------------------------------------------------------------------
// MFMA GEMM: Y[M][256] (bf16) = X[M][256] (fp32) @ W (via Wt[n][k] bf16)
// ---------------------------------------------------------------------------
__global__ __launch_bounds__(256) void mfma_gemm(
    const float* __restrict__ X, const unsigned short* __restrict__ Wt,
    unsigned short* __restrict__ Y, int M)
{
    const int wv = threadIdx.x >> 6, lane = threadIdx.x & 63;
    const int row0 = blockIdx.x * 64 + wv * 16;
    const int r = lane & 15, g = lane >> 4;

    f32x4 acc[16];
#pragma unroll
    for (int t = 0; t < 16; t++) acc[t] = (f32x4){0.f, 0.f, 0.f, 0.f};

    int arow = row0 + r; if (arow >= M) arow = M - 1;

#pragma unroll
    for (int k0 = 0; k0 < 256; k0 += 32) {
        const float* xp = X + (size_t)arow * CH + k0 + g * 8;
        float4 f0 = *(const float4*)(xp);
        float4 f1 = *(const float4*)(xp + 4);
        s16x8 a;
        a[0] = f2bf(f0.x); a[1] = f2bf(f0.y); a[2] = f2bf(f0.z); a[3] = f2bf(f0.w);
        a[4] = f2bf(f1.x); a[5] = f2bf(f1.y); a[6] = f2bf(f1.z); a[7] = f2bf(f1.w);
#pragma unroll
        for (int t = 0; t < 16; t++) {
            s16x8 b = *(const s16x8*)(Wt + (size_t)(t * 16 + r) * CH + k0 + g * 8);
            acc[t] = __builtin_amdgcn_mfma_f32_16x16x32_bf16(a, b, acc[t], 0, 0, 0);
        }
    }

    const int drow0 = row0 + g * 4;
#pragma unroll
    for (int t = 0; t < 16; t++) {
        int col = t * 16 + r;
#pragma unroll
        for (int j = 0; j < 4; j++) {
            int dr = drow0 + j;
            if (dr < M) Y[(size_t)dr * CH + col] = f2bf(acc[t][j]);
        }
    }
}

// ---------------------------------------------------------------------------
// CSR gather SpMM (bf16 rows): O[r] = act( sum_i val[i]*S[col[i]] ), unroll x8
// ---------------------------------------------------------------------------
__global__ __launch_bounds__(256) void gather_csr(
    const int* __restrict__ sd, const int* __restrict__ col,
    const float* __restrict__ val, const unsigned short* __restrict__ S,
    void* __restrict__ O, int n_rows, int sig, int out_bf)
{
    int r    = (int)((blockIdx.x * 256u + threadIdx.x) >> 6);
    int lane = threadIdx.x & 63;
    if (r >= n_rows) return;
    r = __builtin_amdgcn_readfirstlane(r);

    unsigned sdv = (unsigned)sd[r];
    int base = (int)(sdv & 0xFFFFFu), deg = (int)(sdv >> 20);
    const int lo = lane * 4;

    float4 acc = make_float4(0.f, 0.f, 0.f, 0.f);
    int i = 0;
    for (; i + 8 <= deg; i += 8) {
        int   c[8]; float v[8]; ushort4 s[8];
#pragma unroll
        for (int q = 0; q < 8; q++) { c[q] = col[base+i+q]; v[q] = val[base+i+q]; }
#pragma unroll
        for (int q = 0; q < 8; q++) s[q] = *(const ushort4*)(S + (size_t)c[q] * CH + lo);
#pragma unroll
        for (int q = 0; q < 8; q++) {
            acc.x = fmaf(v[q], bf2f(s[q].x), acc.x);
            acc.y = fmaf(v[q], bf2f(s[q].y), acc.y);
            acc.z = fmaf(v[q], bf2f(s[q].z), acc.z);
            acc.w = fmaf(v[q], bf2f(s[q].w), acc.w);
        }
    }
    for (; i + 4 <= deg; i += 4) {
        int   c[4]; float v[4]; ushort4 s[4];
#pragma unroll
        for (int q = 0; q < 4; q++) { c[q] = col[base+i+q]; v[q] = val[base+i+q]; }
#pragma unroll
        for (int q = 0; q < 4; q++) s[q] = *(const ushort4*)(S + (size_t)c[q] * CH + lo);
#pragma unroll
        for (int q = 0; q < 4; q++) {
            acc.x = fmaf(v[q], bf2f(s[q].x), acc.x);
            acc.y = fmaf(v[q], bf2f(s[q].y), acc.y);
            acc.z = fmaf(v[q], bf2f(s[q].z), acc.z);
            acc.w = fmaf(v[q], bf2f(s[q].w), acc.w);
        }
    }
    for (; i < deg; i++) {
        int   c = col[base+i];
        float v = val[base+i];
        ushort4 s = *(const ushort4*)(S + (size_t)c * CH + lo);
        acc.x = fmaf(v, bf2f(s.x), acc.x);
        acc.y = fmaf(v, bf2f(s.y), acc.y);
        acc.z = fmaf(v, bf2f(s.z), acc.z);
        acc.w = fmaf(v, bf2f(s.w), acc.w);
    }
    if (sig) {
        acc.x = sigmoidf_(acc.x); acc.y = sigmoidf_(acc.y);
        acc.z = sigmoidf_(acc.z); acc.w = sigmoidf_(acc.w);
    }
    if (out_bf) {
        ushort4 o; o.x = f2bf(acc.x); o.y = f2bf(acc.y); o.z = f2bf(acc.z); o.w = f2bf(acc.w);
        *(ushort4*)((unsigned short*)O + (size_t)r * CH + lo) = o;
    } else {
        *(float4*)((float*)O + (size_t)r * CH + lo) = acc;
    }
}

// ---------------------------------------------------------------------------
// Edge branch via double CSR (R6 form)
// ---------------------------------------------------------------------------
__global__ __launch_bounds__(256) void edge_gather_csr(
    const int* __restrict__ sd_n, const int* __restrict__ edge_n,
    const float* __restrict__ val_n,
    const int* __restrict__ sd_e, const int* __restrict__ node_e,
    const float* __restrict__ val_e,
    const unsigned short* __restrict__ B, float* __restrict__ F, int n_nodes)
{
    int n    = (int)((blockIdx.x * 256u + threadIdx.x) >> 6);
    int lane = threadIdx.x & 63;
    if (n >= n_nodes) return;
    n = __builtin_amdgcn_readfirstlane(n);

    unsigned sdn = (unsigned)sd_n[n];
    int baseN = (int)(sdn & 0xFFFFFu), degN = (int)(sdn >> 20);
    const int lo = lane * 4;

    float4 acc = make_float4(0.f, 0.f, 0.f, 0.f);
    for (int i = 0; i < degN; i++) {
        int   e = edge_n[baseN + i];
        float v = val_n[baseN + i];
        unsigned sde = (unsigned)sd_e[e];
        int baseE = (int)(sde & 0xFFFFFu), degE = (int)(sde >> 20);

        float4 d = make_float4(0.f, 0.f, 0.f, 0.f);
        int j = 0;
        for (; j + 2 <= degE; j += 2) {
            int   m0 = node_e[baseE+j],   m1 = node_e[baseE+j+1];
            float u0 = val_e[baseE+j],    u1 = val_e[baseE+j+1];
            ushort4 b0 = *(const ushort4*)(B + (size_t)m0 * CH + lo);
            ushort4 b1 = *(const ushort4*)(B + (size_t)m1 * CH + lo);
            d.x += u0*bf2f(b0.x) + u1*bf2f(b1.x);
            d.y += u0*bf2f(b0.y) + u1*bf2f(b1.y);
            d.z += u0*bf2f(b0.z) + u1*bf2f(b1.z);
            d.w += u0*bf2f(b0.w) + u1*bf2f(b1.w);
        }
        for (; j < degE; j++) {
            int   m = node_e[baseE+j];
            float u = val_e[baseE+j];
            ushort4 b = *(const ushort4*)(B + (size_t)m * CH + lo);
            d.x = fmaf(u, bf2f(b.x), d.x);
            d.y = fmaf(u, bf2f(b.y), d.y);
            d.z = fmaf(u, bf2f(b.z), d.z);
            d.w = fmaf(u, bf2f(b.w), d.w);
        }
        acc.x = fmaf(v, sigmoidf_(d.x), acc.x);
        acc.y = fmaf(v, sigmoidf_(d.y), acc.y);
        acc.z = fmaf(v, sigmoidf_(d.z), acc.z);
        acc.w = fmaf(v, sigmoidf_(d.w), acc.w);
    }
    *(float4*)(F + (size_t)n * CH + lo) = acc;
}

// ---------------------------------------------------------------------------
// Final GEMM, split-bf16 MFMA, fp32-equivalent, weight-stationary via LDS.
// R7/R8 regression root cause (rule #20): `#pragma unroll 4` made t runtime ->
// acc[gr][t] demoted to scratch (VGPR=88, WRITE_SIZE=498MB). FULL unroll keeps
// every acc index compile-time-constant -> acc stays in registers.
// ---------------------------------------------------------------------------
__device__ __forceinline__ void split8(float4 a, float4 b, s16x8& hi, s16x8& lo)
{
    float v[8] = {a.x, a.y, a.z, a.w, b.x, b.y, b.z, b.w};
#pragma unroll
    for (int i = 0; i < 8; i++) {
        unsigned short h = f2bf(v[i]);
        hi[i] = (short)h;
        lo[i] = (short)f2bf(v[i] - bf2f(h));
    }
}

__global__ __launch_bounds__(256, 2) void final_mfma(
    const float* __restrict__ E, const float* __restrict__ F,
    const unsigned short* __restrict__ Wh10, const unsigned short* __restrict__ Wl10,
    const unsigned short* __restrict__ Wh11, const unsigned short* __restrict__ Wl11,
    float* __restrict__ Y, int M)
{
    __shared__ unsigned short lds[4 * 4 * 257 * 8];   // 65792 B (2 blocks/CU)
    const int tid = threadIdx.x;
    const int wv = tid >> 6, lane = tid & 63;
    const int row0 = blockIdx.x * 128 + wv * 32;
    const int r = lane & 15, g = lane >> 4;

    f32x4 acc[2][16];
#pragma unroll
    for (int gr = 0; gr < 2; gr++)
#pragma unroll
        for (int t = 0; t < 16; t++) acc[gr][t] = (f32x4){0.f, 0.f, 0.f, 0.f};

    int ar0 = row0 + r;      if (ar0 >= M) ar0 = M - 1;
    int ar1 = row0 + 16 + r; if (ar1 >= M) ar1 = M - 1;

    for (int k0i = 0; k0i < 8; ++k0i) {
        const int kbase = k0i * 32 + g * 8;
        // issue E/F global loads early (overlap LDS staging)
        const float* p = E + (size_t)ar0 * CH + kbase;
        float4 e0a = *(const float4*)p, e0b = *(const float4*)(p + 4);
        p = E + (size_t)ar1 * CH + kbase;
        float4 e1a = *(const float4*)p, e1b = *(const float4*)(p + 4);
        p = F + (size_t)ar0 * CH + kbase;
        float4 f0a = *(const float4*)p, f0b = *(const float4*)(p + 4);
        p = F + (size_t)ar1 * CH + kbase;
        float4 f1a = *(const float4*)p, f1b = *(const float4*)(p + 4);

        if (k0i) __syncthreads();   // previous slice's LDS reads complete
#pragma unroll
        for (int m = 0; m < 4; m++) {
            const unsigned short* src =
                (m == 0) ? Wh10 : (m == 1) ? Wl10 : (m == 2) ? Wh11 : Wl11;
            src += (size_t)k0i * 1024 * 8;
#pragma unroll
            for (int g2 = 0; g2 < 4; g2++) {
                int frag = (m * 4 + g2) * 257 + tid;
                *(s16x8*)&lds[frag * 8] = *(const s16x8*)(src + (size_t)(g2 * 256 + tid) * 8);
            }
        }
        __syncthreads();

        s16x8 eh0, el0, eh1, el1, fh0, fl0, fh1, fl1;
        split8(e0a, e0b, eh0, el0);
        split8(e1a, e1b, eh1, el1);
        split8(f0a, f0b, fh0, fl0);
        split8(f1a, f1b, fh1, fl1);

#pragma unroll
        for (int t = 0; t < 16; t++) {
            int rr = t * 16 + r;
            s16x8 bh0 = *(const s16x8*)&lds[((0 + g) * 257 + rr) * 8];
            s16x8 bl0 = *(const s16x8*)&lds[((4 + g) * 257 + rr) * 8];
            s16x8 bh1 = *(const s16x8*)&lds[((8 + g) * 257 + rr) * 8];
            s16x8 bl1 = *(const s16x8*)&lds[((12 + g) * 257 + rr) * 8];

            acc[0][t] = __builtin_amdgcn_mfma_f32_16x16x32_bf16(eh0, bh0, acc[0][t], 0, 0, 0);
            acc[0][t] = __builtin_amdgcn_mfma_f32_16x16x32_bf16(el0, bh0, acc[0][t], 0, 0, 0);
            acc[0][t] = __builtin_amdgcn_mfma_f32_16x16x32_bf16(eh0, bl0, acc[0][t], 0, 0, 0);
            acc[0][t] = __builtin_amdgcn_mfma_f32_16x16x32_bf16(fh0, bh1, acc[0][t], 0, 0, 0);
            acc[0][t] = __builtin_amdgcn_mfma_f32_16x16x32_bf16(fl0, bh1, acc[0][t], 0, 0, 0);
            acc[0][t] = __builtin_amdgcn_mfma_f32_16x16x32_bf16(fh0, bl1, acc[0][t], 0, 0, 0);

            acc[1][t] = __builtin_amdgcn_mfma_f32_16x16x32_bf16(eh1, bh0, acc[1][t], 0, 0, 0);
            acc[1][t] = __builtin_amdgcn_mfma_f32_16x16x32_bf16(el1, bh0, acc[1][t], 0, 0, 0);
            acc[1][t] = __builtin_amdgcn_mfma_f32_16x16x32_bf16(eh1, bl0, acc[1][t], 0, 0, 0);
            acc[1][t] = __builtin_amdgcn_mfma_f32_16x16x32_bf16(fh1, bh1, acc[1][t], 0, 0, 0);
            acc[1][t] = __builtin_amdgcn_mfma_f32_16x16x32_bf16(fl1, bh1, acc[1][t], 0, 0, 0);
            acc[1][t] = __builtin_amdgcn_mfma_f32_16x16x32_bf16(fh1, bl1, acc[1][t], 0, 0, 0);
        }
    }

#pragma unroll
    for (int gr = 0; gr < 2; gr++) {
        const int drow0 = row0 + gr * 16 + g * 4;
#pragma unroll
        for (int t = 0; t < 16; t++) {
            int col = t * 16 + r;
#pragma unroll
            for (int j = 0; j < 4; j++) {
                int dr = drow0 + j;
                if (dr < M) Y[(size_t)dr * CH + col] = sigmoidf_(acc[gr][t][j]);
            }
        }
    }
}

// ---------------------------------------------------------------------------
extern "C" void kernel_launch(void* const* d_in, const int* in_sizes, int n_in,
                              void* d_out, int out_size, void* d_ws, size_t ws_size,
                              hipStream_t stream)
{
    const float* x        = (const float*)d_in[0];
    const int*   adj_rows = (const int*)  d_in[1];
    const int*   adj_cols = (const int*)  d_in[2];
    const float* adj_vals = (const float*)d_in[3];
    const int*   inc_rows = (const int*)  d_in[4];
    const int*   inc_cols = (const int*)  d_in[5];
    const float* inc_vals = (const float*)d_in[6];
    const float* W00      = (const float*)d_in[7];
    const float* W01      = (const float*)d_in[8];
    const float* W10      = (const float*)d_in[9];
    const float* W11      = (const float*)d_in[10];

    // -------- workspace layout (110.4 MB total; proven-safe < 114.26 MB) ----
    const size_t SZ_AB = (size_t)N_NODES * CH * 2;    // 25.6 MB
    const size_t SZ_F  = (size_t)N_NODES * CH * 4;    // 51.2 MB
    char* ws = (char*)d_ws;
    size_t off = 0;
    unsigned short* AB_bf = (unsigned short*)(ws + off); off += SZ_AB;
    float*          F     = (float*)(ws + off);          off += SZ_F;
    int*   sd_a  = (int*)(ws + off);  off += (size_t)N_NODES * 4;
    int*   col_a = (int*)(ws + off);  off += (size_t)NNZ * 4;
    float* val_a = (float*)(ws + off); off += (size_t)NNZ * 4;
    int*   cursors = (int*)(ws + off); off += 256;
    unsigned short* Wt00  = (unsigned short*)(ws + off); off += (size_t)CH * CH * 2;
    unsigned short* Wt01  = (unsigned short*)(ws + off); off += (size_t)CH * CH * 2;
    unsigned short* Wh10  = (unsigned short*)(ws + off); off += (size_t)CH * CH * 2;
    unsigned short* Wl10  = (unsigned short*)(ws + off); off += (size_t)CH * CH * 2;
    unsigned short* Wh11  = (unsigned short*)(ws + off); off += (size_t)CH * CH * 2;
    unsigned short* Wl11  = (unsigned short*)(ws + off); off += (size_t)CH * CH * 2;
    // scratch: lists + inc CSRs (dead after edge_gather_csr); C_bf overlays it
    char* scratch = ws + off;
    int*   head_a = (int*)(scratch);
    int*   head_e = head_a + N_NODES;
    int*   head_n = head_e + N_EDGES;
    int*   nxt_a  = head_n + N_NODES;
    int*   nxt_e  = nxt_a + NNZ;
    int*   nxt_n  = nxt_e + NNZ;
    int*   sd_n   = nxt_n + NNZ;
    int*   edge_n = sd_n + N_NODES;
    float* val_n  = (float*)(edge_n + NNZ);
    int*   sd_e   = (int*)(val_n + NNZ);
    int*   node_e = sd_e + N_EDGES;
    float* val_e  = (float*)(node_e + NNZ);
    unsigned short* C_bf = (unsigned short*)scratch;
    float* E = (float*)d_out;

    const int gemm_blocks  = (N_NODES + 63) / 64;          // 782
    const int final_blocks = (N_NODES + 127) / 128;        // 391
    const int row_blocks   = (N_NODES * 64 + 255) / 256;   // 12500
    const int list_blocks  = (NNZ + 255) / 256;

    // 0) lists -> CSR + weight transposes (frag-packed hi/lo for W10/W11)
    fill_i32<<<1024, 256, 0, stream>>>(head_a, -1, N_NODES + N_EDGES + N_NODES);
    fill_i32<<<1, 64, 0, stream>>>(cursors, 0, 3);
    build_list<<<list_blocks, 256, 0, stream>>>(adj_rows, head_a, nxt_a, NNZ);
    build_list<<<list_blocks, 256, 0, stream>>>(inc_cols, head_e, nxt_e, NNZ);
    build_list<<<list_blocks, 256, 0, stream>>>(inc_rows, head_n, nxt_n, NNZ);
    pack_csr<<<(N_NODES + 255) / 256, 256, 0, stream>>>(
        head_a, nxt_a, adj_cols, adj_vals, sd_a, col_a, val_a, cursors + 0, N_NODES);
    pack_csr<<<(N_EDGES + 255) / 256, 256, 0, stream>>>(
        head_e, nxt_e, inc_rows, inc_vals, sd_e, node_e, val_e, cursors + 1, N_EDGES);
    pack_csr<<<(N_NODES + 255) / 256, 256, 0, stream>>>(
        head_n, nxt_n, inc_cols, inc_vals, sd_n, edge_n, val_n, cursors + 2, N_NODES);
    cvt_w_transpose<<<256, 256, 0, stream>>>(W00, W01, Wt00, Wt01);
    cvt_w_hilo_pk<<<256, 256, 0, stream>>>(W10, Wh10, Wl10);
    cvt_w_hilo_pk<<<256, 256, 0, stream>>>(W11, Wh11, Wl11);

    // 1) B = x @ W01  (bf16, MFMA)
    mfma_gemm<<<gemm_blocks, 256, 0, stream>>>(x, Wt01, AB_bf, N_NODES);

    // 2) F[n] = sum v * sigmoid(D_e)  (double-CSR, registers only)
    edge_gather_csr<<<row_blocks, 256, 0, stream>>>(sd_n, edge_n, val_n,
                                                    sd_e, node_e, val_e,
                                                    AB_bf, F, N_NODES);

    // 3) A = x @ W00  (overwrites B — dead)
    mfma_gemm<<<gemm_blocks, 256, 0, stream>>>(x, Wt00, AB_bf, N_NODES);

    // 4) C = sigmoid(gather_adj(A)) -> bf16  (overlays dead scratch)
    gather_csr<<<row_blocks, 256, 0, stream>>>(sd_a, col_a, val_a,
                                               AB_bf, C_bf, N_NODES, 1, 1);

    // 5) E = gather_adj(C) -> fp32 in d_out
    gather_csr<<<row_blocks, 256, 0, stream>>>(sd_a, col_a, val_a,
                                               C_bf, E, N_NODES, 0, 0);

    // 6) out = sigmoid(E @ W10 + F @ W11)  (split-bf16 MFMA, LDS weight-stationary,
    //    in-place on d_out: each block reads only its own rows pre-write)
    final_mfma<<<final_blocks, 256, 0, stream>>>(E, F, Wh10, Wl10, Wh11, Wl11,
                                                 (float*)d_out, N_NODES);
}

// Round 10
// 874.196 us; speedup vs baseline: 1.2653x; 1.0659x over previous
//
#include <hip/hip_runtime.h>
#include <math.h>

#define N_NODES 50000
#define N_EDGES 400000
#define CH      256
#define NNZ     800000

typedef short s16x8 __attribute__((ext_vector_type(8)));
typedef float f32x4 __attribute__((ext_vector_type(4)));

__device__ __forceinline__ float sigmoidf_(float x) {
    return 1.0f / (1.0f + __expf(-x));
}
__device__ __forceinline__ unsigned short f2bf(float f) {
    unsigned u = __float_as_uint(f);
    u = (u + 0x7FFFu + ((u >> 16) & 1u)) >> 16;   // RNE
    return (unsigned short)u;
}
__device__ __forceinline__ float bf2f(unsigned short h) {
    return __uint_as_float((unsigned)h << 16);
}

// ---------------------------------------------------------------------------
__global__ __launch_bounds__(256) void fill_i32(int* __restrict__ p, int val, int n)
{
    int stride = gridDim.x * 256;
    for (int i = blockIdx.x * 256 + threadIdx.x; i < n; i += stride) p[i] = val;
}

// Build all three linked-list groupings in one launch (blockIdx.y selects).
__global__ __launch_bounds__(256) void build3(
    const int* __restrict__ k0, int* __restrict__ h0, int* __restrict__ x0,
    const int* __restrict__ k1, int* __restrict__ h1, int* __restrict__ x1,
    const int* __restrict__ k2, int* __restrict__ h2, int* __restrict__ x2, int n)
{
    int i = blockIdx.x * 256 + threadIdx.x;
    if (i >= n) return;
    const int* key; int* head; int* nxt;
    if      (blockIdx.y == 0) { key = k0; head = h0; nxt = x0; }
    else if (blockIdx.y == 1) { key = k1; head = h1; nxt = x1; }
    else                      { key = k2; head = h2; nxt = x2; }
    nxt[i] = atomicExch(&head[key[i]], i);
}

// Linked list -> packed CSR (no scan): sd[k] = base | (deg<<20).
struct PackArgs {
    const int* head; const int* nxt; const int* other; const float* vals;
    int* sd; int* col; float* val; int* cursor; int nkeys;
};

__global__ __launch_bounds__(256) void pack3(PackArgs a0, PackArgs a1, PackArgs a2)
{
    PackArgs a = (blockIdx.y == 0) ? a0 : (blockIdx.y == 1) ? a1 : a2;
    int k = blockIdx.x * 256 + threadIdx.x;
    if (k >= a.nkeys) return;
    int deg = 0;
    for (int p = a.head[k]; p >= 0; p = a.nxt[p]) deg++;
    int base = deg ? atomicAdd(a.cursor, deg) : 0;
    a.sd[k] = base | (deg << 20);
    int i = base;
    for (int p = a.head[k]; p >= 0; p = a.nxt[p]) {
        a.col[i] = a.other[p];
        a.val[i] = a.vals[p];
        i++;
    }
}

// Pre-resolve edge descriptors into the node-grouped entry stream:
// edge_n[p] <- sd_e[edge_n[p]]. Removes one dependent random load per outer
// iteration from the hot edge kernel's latency chain.
__global__ __launch_bounds__(256) void resolve_desc(
    int* __restrict__ edge_n, const int* __restrict__ sd_e, int n)
{
    int i = blockIdx.x * 256 + threadIdx.x;
    if (i < n) edge_n[i] = sd_e[edge_n[i]];
}

// All weight conversions in one launch: y=0 -> Wt00, y=1 -> Wt01 (transposed
// bf16), y=2 -> W10 hi/lo frag-packed, y=3 -> W11 hi/lo frag-packed.
__global__ __launch_bounds__(256) void cvt_all(
    const float* __restrict__ W00, const float* __restrict__ W01,
    const float* __restrict__ W10, const float* __restrict__ W11,
    unsigned short* __restrict__ T0, unsigned short* __restrict__ T1,
    unsigned short* __restrict__ Wh10, unsigned short* __restrict__ Wl10,
    unsigned short* __restrict__ Wh11, unsigned short* __restrict__ Wl11)
{
    int n = blockIdx.x, k = threadIdx.x, y = blockIdx.y;
    if (y == 0) { T0[n * 256 + k] = f2bf(W00[k * 256 + n]); return; }
    if (y == 1) { T1[n * 256 + k] = f2bf(W01[k * 256 + n]); return; }
    const float* W = (y == 2) ? W10 : W11;
    unsigned short* Th = (y == 2) ? Wh10 : Wh11;
    unsigned short* Tl = (y == 2) ? Wl10 : Wl11;
    float w = W[k * 256 + n];
    unsigned short h = f2bf(w);
    int k0i = k >> 5, g = (k >> 3) & 3, j = k & 7;
    size_t o = (((size_t)(k0i * 4 + g)) * 256 + n) * 8 + j;
    Th[o] = h;
    Tl[o] = f2bf(w - bf2f(h));
}

// ---------------------------------------------------------------------------
// Fused dual-output MFMA GEMM: Y0 = X@W0, Y1 = X@W1 (bf16 out). Shares the
// x read and the fp32->bf16 A-frag conversion between both products.
// ---------------------------------------------------------------------------
__global__ __launch_bounds__(256, 2) void mfma_gemm2(
    const float* __restrict__ X,
    const unsigned short* __restrict__ Wt0, const unsigned short* __restrict__ Wt1,
    unsigned short* __restrict__ Y0, unsigned short* __restrict__ Y1, int M)
{
    const int wv = threadIdx.x >> 6, lane = threadIdx.x & 63;
    const int row0 = blockIdx.x * 64 + wv * 16;
    const int r = lane & 15, g = lane >> 4;

    f32x4 acc0[16], acc1[16];
#pragma unroll
    for (int t = 0; t < 16; t++) {
        acc0[t] = (f32x4){0.f, 0.f, 0.f, 0.f};
        acc1[t] = (f32x4){0.f, 0.f, 0.f, 0.f};
    }

    int arow = row0 + r; if (arow >= M) arow = M - 1;

#pragma unroll
    for (int k0 = 0; k0 < 256; k0 += 32) {
        const float* xp = X + (size_t)arow * CH + k0 + g * 8;
        float4 f0 = *(const float4*)(xp);
        float4 f1 = *(const float4*)(xp + 4);
        s16x8 a;
        a[0] = f2bf(f0.x); a[1] = f2bf(f0.y); a[2] = f2bf(f0.z); a[3] = f2bf(f0.w);
        a[4] = f2bf(f1.x); a[5] = f2bf(f1.y); a[6] = f2bf(f1.z); a[7] = f2bf(f1.w);
#pragma unroll
        for (int t = 0; t < 16; t++) {
            size_t wo = (size_t)(t * 16 + r) * CH + k0 + g * 8;
            s16x8 b0 = *(const s16x8*)(Wt0 + wo);
            acc0[t] = __builtin_amdgcn_mfma_f32_16x16x32_bf16(a, b0, acc0[t], 0, 0, 0);
            s16x8 b1 = *(const s16x8*)(Wt1 + wo);
            acc1[t] = __builtin_amdgcn_mfma_f32_16x16x32_bf16(a, b1, acc1[t], 0, 0, 0);
        }
    }

    const int drow0 = row0 + g * 4;
#pragma unroll
    for (int t = 0; t < 16; t++) {
        int col = t * 16 + r;
#pragma unroll
        for (int j = 0; j < 4; j++) {
            int dr = drow0 + j;
            if (dr < M) {
                Y0[(size_t)dr * CH + col] = f2bf(acc0[t][j]);
                Y1[(size_t)dr * CH + col] = f2bf(acc1[t][j]);
            }
        }
    }
}

// ---------------------------------------------------------------------------
// CSR gather SpMM (bf16 rows): O[r] = act( sum_i val[i]*S[col[i]] ), unroll x8
// ---------------------------------------------------------------------------
__global__ __launch_bounds__(256) void gather_csr(
    const int* __restrict__ sd, const int* __restrict__ col,
    const float* __restrict__ val, const unsigned short* __restrict__ S,
    void* __restrict__ O, int n_rows, int sig, int out_bf)
{
    int r    = (int)((blockIdx.x * 256u + threadIdx.x) >> 6);
    int lane = threadIdx.x & 63;
    if (r >= n_rows) return;
    r = __builtin_amdgcn_readfirstlane(r);

    unsigned sdv = (unsigned)sd[r];
    int base = (int)(sdv & 0xFFFFFu), deg = (int)(sdv >> 20);
    const int lo = lane * 4;

    float4 acc = make_float4(0.f, 0.f, 0.f, 0.f);
    int i = 0;
    for (; i + 8 <= deg; i += 8) {
        int   c[8]; float v[8]; ushort4 s[8];
#pragma unroll
        for (int q = 0; q < 8; q++) { c[q] = col[base+i+q]; v[q] = val[base+i+q]; }
#pragma unroll
        for (int q = 0; q < 8; q++) s[q] = *(const ushort4*)(S + (size_t)c[q] * CH + lo);
#pragma unroll
        for (int q = 0; q < 8; q++) {
            acc.x = fmaf(v[q], bf2f(s[q].x), acc.x);
            acc.y = fmaf(v[q], bf2f(s[q].y), acc.y);
            acc.z = fmaf(v[q], bf2f(s[q].z), acc.z);
            acc.w = fmaf(v[q], bf2f(s[q].w), acc.w);
        }
    }
    for (; i + 4 <= deg; i += 4) {
        int   c[4]; float v[4]; ushort4 s[4];
#pragma unroll
        for (int q = 0; q < 4; q++) { c[q] = col[base+i+q]; v[q] = val[base+i+q]; }
#pragma unroll
        for (int q = 0; q < 4; q++) s[q] = *(const ushort4*)(S + (size_t)c[q] * CH + lo);
#pragma unroll
        for (int q = 0; q < 4; q++) {
            acc.x = fmaf(v[q], bf2f(s[q].x), acc.x);
            acc.y = fmaf(v[q], bf2f(s[q].y), acc.y);
            acc.z = fmaf(v[q], bf2f(s[q].z), acc.z);
            acc.w = fmaf(v[q], bf2f(s[q].w), acc.w);
        }
    }
    for (; i < deg; i++) {
        int   c = col[base+i];
        float v = val[base+i];
        ushort4 s = *(const ushort4*)(S + (size_t)c * CH + lo);
        acc.x = fmaf(v, bf2f(s.x), acc.x);
        acc.y = fmaf(v, bf2f(s.y), acc.y);
        acc.z = fmaf(v, bf2f(s.z), acc.z);
        acc.w = fmaf(v, bf2f(s.w), acc.w);
    }
    if (sig) {
        acc.x = sigmoidf_(acc.x); acc.y = sigmoidf_(acc.y);
        acc.z = sigmoidf_(acc.z); acc.w = sigmoidf_(acc.w);
    }
    if (out_bf) {
        ushort4 o; o.x = f2bf(acc.x); o.y = f2bf(acc.y); o.z = f2bf(acc.z); o.w = f2bf(acc.w);
        *(ushort4*)((unsigned short*)O + (size_t)r * CH + lo) = o;
    } else {
        *(float4*)((float*)O + (size_t)r * CH + lo) = acc;
    }
}

// ---------------------------------------------------------------------------
// Edge branch via double CSR with PRE-RESOLVED descriptors: edge_n[p] already
// holds (baseE | degE<<20), so the hot chain is 2 levels (stream -> B row)
// instead of 3 (stream -> sd_e -> B row).
// ---------------------------------------------------------------------------
__global__ __launch_bounds__(256) void edge_gather_csr(
    const int* __restrict__ sd_n, const int* __restrict__ edge_n,
    const float* __restrict__ val_n,
    const int* __restrict__ node_e, const float* __restrict__ val_e,
    const unsigned short* __restrict__ B, float* __restrict__ F, int n_nodes)
{
    int n    = (int)((blockIdx.x * 256u + threadIdx.x) >> 6);
    int lane = threadIdx.x & 63;
    if (n >= n_nodes) return;
    n = __builtin_amdgcn_readfirstlane(n);

    unsigned sdn = (unsigned)sd_n[n];
    int baseN = (int)(sdn & 0xFFFFFu), degN = (int)(sdn >> 20);
    const int lo = lane * 4;

    float4 acc = make_float4(0.f, 0.f, 0.f, 0.f);
    for (int i = 0; i < degN; i++) {
        unsigned sde = (unsigned)edge_n[baseN + i];   // pre-resolved descriptor
        float v = val_n[baseN + i];
        int baseE = (int)(sde & 0xFFFFFu), degE = (int)(sde >> 20);

        float4 d = make_float4(0.f, 0.f, 0.f, 0.f);
        int j = 0;
        for (; j + 2 <= degE; j += 2) {
            int   m0 = node_e[baseE+j],   m1 = node_e[baseE+j+1];
            float u0 = val_e[baseE+j],    u1 = val_e[baseE+j+1];
            ushort4 b0 = *(const ushort4*)(B + (size_t)m0 * CH + lo);
            ushort4 b1 = *(const ushort4*)(B + (size_t)m1 * CH + lo);
            d.x += u0*bf2f(b0.x) + u1*bf2f(b1.x);
            d.y += u0*bf2f(b0.y) + u1*bf2f(b1.y);
            d.z += u0*bf2f(b0.z) + u1*bf2f(b1.z);
            d.w += u0*bf2f(b0.w) + u1*bf2f(b1.w);
        }
        for (; j < degE; j++) {
            int   m = node_e[baseE+j];
            float u = val_e[baseE+j];
            ushort4 b = *(const ushort4*)(B + (size_t)m * CH + lo);
            d.x = fmaf(u, bf2f(b.x), d.x);
            d.y = fmaf(u, bf2f(b.y), d.y);
            d.z = fmaf(u, bf2f(b.z), d.z);
            d.w = fmaf(u, bf2f(b.w), d.w);
        }
        acc.x = fmaf(v, sigmoidf_(d.x), acc.x);
        acc.y = fmaf(v, sigmoidf_(d.y), acc.y);
        acc.z = fmaf(v, sigmoidf_(d.z), acc.z);
        acc.w = fmaf(v, sigmoidf_(d.w), acc.w);
    }
    *(float4*)(F + (size_t)n * CH + lo) = acc;
}

// ---------------------------------------------------------------------------
// Final GEMM, split-bf16 MFMA, fp32-equivalent, weight-stationary via LDS.
// FULL unroll on the t-loop (rule #20: partial unroll demotes acc to scratch).
// ---------------------------------------------------------------------------
__device__ __forceinline__ void split8(float4 a, float4 b, s16x8& hi, s16x8& lo)
{
    float v[8] = {a.x, a.y, a.z, a.w, b.x, b.y, b.z, b.w};
#pragma unroll
    for (int i = 0; i < 8; i++) {
        unsigned short h = f2bf(v[i]);
        hi[i] = (short)h;
        lo[i] = (short)f2bf(v[i] - bf2f(h));
    }
}

__global__ __launch_bounds__(256, 2) void final_mfma(
    const float* __restrict__ E, const float* __restrict__ F,
    const unsigned short* __restrict__ Wh10, const unsigned short* __restrict__ Wl10,
    const unsigned short* __restrict__ Wh11, const unsigned short* __restrict__ Wl11,
    float* __restrict__ Y, int M)
{
    __shared__ unsigned short lds[4 * 4 * 257 * 8];   // 65792 B (2 blocks/CU)
    const int tid = threadIdx.x;
    const int wv = tid >> 6, lane = tid & 63;
    const int row0 = blockIdx.x * 128 + wv * 32;
    const int r = lane & 15, g = lane >> 4;

    f32x4 acc[2][16];
#pragma unroll
    for (int gr = 0; gr < 2; gr++)
#pragma unroll
        for (int t = 0; t < 16; t++) acc[gr][t] = (f32x4){0.f, 0.f, 0.f, 0.f};

    int ar0 = row0 + r;      if (ar0 >= M) ar0 = M - 1;
    int ar1 = row0 + 16 + r; if (ar1 >= M) ar1 = M - 1;

    for (int k0i = 0; k0i < 8; ++k0i) {
        const int kbase = k0i * 32 + g * 8;
        const float* p = E + (size_t)ar0 * CH + kbase;
        float4 e0a = *(const float4*)p, e0b = *(const float4*)(p + 4);
        p = E + (size_t)ar1 * CH + kbase;
        float4 e1a = *(const float4*)p, e1b = *(const float4*)(p + 4);
        p = F + (size_t)ar0 * CH + kbase;
        float4 f0a = *(const float4*)p, f0b = *(const float4*)(p + 4);
        p = F + (size_t)ar1 * CH + kbase;
        float4 f1a = *(const float4*)p, f1b = *(const float4*)(p + 4);

        if (k0i) __syncthreads();
#pragma unroll
        for (int m = 0; m < 4; m++) {
            const unsigned short* src =
                (m == 0) ? Wh10 : (m == 1) ? Wl10 : (m == 2) ? Wh11 : Wl11;
            src += (size_t)k0i * 1024 * 8;
#pragma unroll
            for (int g2 = 0; g2 < 4; g2++) {
                int frag = (m * 4 + g2) * 257 + tid;
                *(s16x8*)&lds[frag * 8] = *(const s16x8*)(src + (size_t)(g2 * 256 + tid) * 8);
            }
        }
        __syncthreads();

        s16x8 eh0, el0, eh1, el1, fh0, fl0, fh1, fl1;
        split8(e0a, e0b, eh0, el0);
        split8(e1a, e1b, eh1, el1);
        split8(f0a, f0b, fh0, fl0);
        split8(f1a, f1b, fh1, fl1);

#pragma unroll
        for (int t = 0; t < 16; t++) {
            int rr = t * 16 + r;
            s16x8 bh0 = *(const s16x8*)&lds[((0 + g) * 257 + rr) * 8];
            s16x8 bl0 = *(const s16x8*)&lds[((4 + g) * 257 + rr) * 8];
            s16x8 bh1 = *(const s16x8*)&lds[((8 + g) * 257 + rr) * 8];
            s16x8 bl1 = *(const s16x8*)&lds[((12 + g) * 257 + rr) * 8];

            acc[0][t] = __builtin_amdgcn_mfma_f32_16x16x32_bf16(eh0, bh0, acc[0][t], 0, 0, 0);
            acc[0][t] = __builtin_amdgcn_mfma_f32_16x16x32_bf16(el0, bh0, acc[0][t], 0, 0, 0);
            acc[0][t] = __builtin_amdgcn_mfma_f32_16x16x32_bf16(eh0, bl0, acc[0][t], 0, 0, 0);
            acc[0][t] = __builtin_amdgcn_mfma_f32_16x16x32_bf16(fh0, bh1, acc[0][t], 0, 0, 0);
            acc[0][t] = __builtin_amdgcn_mfma_f32_16x16x32_bf16(fl0, bh1, acc[0][t], 0, 0, 0);
            acc[0][t] = __builtin_amdgcn_mfma_f32_16x16x32_bf16(fh0, bl1, acc[0][t], 0, 0, 0);

            acc[1][t] = __builtin_amdgcn_mfma_f32_16x16x32_bf16(eh1, bh0, acc[1][t], 0, 0, 0);
            acc[1][t] = __builtin_amdgcn_mfma_f32_16x16x32_bf16(el1, bh0, acc[1][t], 0, 0, 0);
            acc[1][t] = __builtin_amdgcn_mfma_f32_16x16x32_bf16(eh1, bl0, acc[1][t], 0, 0, 0);
            acc[1][t] = __builtin_amdgcn_mfma_f32_16x16x32_bf16(fh1, bh1, acc[1][t], 0, 0, 0);
            acc[1][t] = __builtin_amdgcn_mfma_f32_16x16x32_bf16(fl1, bh1, acc[1][t], 0, 0, 0);
            acc[1][t] = __builtin_amdgcn_mfma_f32_16x16x32_bf16(fh1, bl1, acc[1][t], 0, 0, 0);
        }
    }

#pragma unroll
    for (int gr = 0; gr < 2; gr++) {
        const int drow0 = row0 + gr * 16 + g * 4;
#pragma unroll
        for (int t = 0; t < 16; t++) {
            int col = t * 16 + r;
#pragma unroll
            for (int j = 0; j < 4; j++) {
                int dr = drow0 + j;
                if (dr < M) Y[(size_t)dr * CH + col] = sigmoidf_(acc[gr][t][j]);
            }
        }
    }
}

// ---------------------------------------------------------------------------
extern "C" void kernel_launch(void* const* d_in, const int* in_sizes, int n_in,
                              void* d_out, int out_size, void* d_ws, size_t ws_size,
                              hipStream_t stream)
{
    const float* x        = (const float*)d_in[0];
    const int*   adj_rows = (const int*)  d_in[1];
    const int*   adj_cols = (const int*)  d_in[2];
    const float* adj_vals = (const float*)d_in[3];
    const int*   inc_rows = (const int*)  d_in[4];
    const int*   inc_cols = (const int*)  d_in[5];
    const float* inc_vals = (const float*)d_in[6];
    const float* W00      = (const float*)d_in[7];
    const float* W01      = (const float*)d_in[8];
    const float* W10      = (const float*)d_in[9];
    const float* W11      = (const float*)d_in[10];

    // -------- workspace layout (~110.5 MB; proven-safe < 114.26 MB) ---------
    // B = x@W01 lives in d_out[0 : 25.6MB] (bf16): d_out is dead until E is
    // written (step 9), and B is consumed (step 7) before that.
    const size_t SZ_AB = (size_t)N_NODES * CH * 2;    // 25.6 MB
    const size_t SZ_F  = (size_t)N_NODES * CH * 4;    // 51.2 MB
    char* ws = (char*)d_ws;
    size_t off = 0;
    unsigned short* A_bf = (unsigned short*)(ws + off); off += SZ_AB;
    float*          F    = (float*)(ws + off);          off += SZ_F;
    int*   sd_a  = (int*)(ws + off);  off += (size_t)N_NODES * 4;
    int*   col_a = (int*)(ws + off);  off += (size_t)NNZ * 4;
    float* val_a = (float*)(ws + off); off += (size_t)NNZ * 4;
    int*   cursors = (int*)(ws + off); off += 256;
    unsigned short* Wt00  = (unsigned short*)(ws + off); off += (size_t)CH * CH * 2;
    unsigned short* Wt01  = (unsigned short*)(ws + off); off += (size_t)CH * CH * 2;
    unsigned short* Wh10  = (unsigned short*)(ws + off); off += (size_t)CH * CH * 2;
    unsigned short* Wl10  = (unsigned short*)(ws + off); off += (size_t)CH * CH * 2;
    unsigned short* Wh11  = (unsigned short*)(ws + off); off += (size_t)CH * CH * 2;
    unsigned short* Wl11  = (unsigned short*)(ws + off); off += (size_t)CH * CH * 2;
    // scratch (26.2 MB): lists + inc CSRs, all dead after edge kernel;
    // C_bf (25.6 MB) overlays it afterwards.
    char* scratch = ws + off;
    int*   head_a = (int*)(scratch);
    int*   head_e = head_a + N_NODES;
    int*   head_n = head_e + N_EDGES;
    int*   nxt_a  = head_n + N_NODES;
    int*   nxt_e  = nxt_a + NNZ;
    int*   nxt_n  = nxt_e + NNZ;
    int*   sd_n   = nxt_n + NNZ;
    int*   edge_n = sd_n + N_NODES;
    float* val_n  = (float*)(edge_n + NNZ);
    int*   sd_e   = (int*)(val_n + NNZ);
    int*   node_e = sd_e + N_EDGES;
    float* val_e  = (float*)(node_e + NNZ);
    unsigned short* C_bf = (unsigned short*)scratch;
    unsigned short* B_bf = (unsigned short*)d_out;
    float* E = (float*)d_out;

    const int gemm_blocks  = (N_NODES + 63) / 64;          // 782
    const int final_blocks = (N_NODES + 127) / 128;        // 391
    const int row_blocks   = (N_NODES * 64 + 255) / 256;   // 12500
    const int list_blocks  = (NNZ + 255) / 256;            // 3125

    // 0) fills + merged grouping builds + packs + descriptor resolve + cvt
    fill_i32<<<1024, 256, 0, stream>>>(head_a, -1, N_NODES + N_EDGES + N_NODES);
    fill_i32<<<1, 64, 0, stream>>>(cursors, 0, 3);
    build3<<<dim3(list_blocks, 3), 256, 0, stream>>>(
        adj_rows, head_a, nxt_a, inc_cols, head_e, nxt_e, inc_rows, head_n, nxt_n, NNZ);
    PackArgs pa{head_a, nxt_a, adj_cols, adj_vals, sd_a, col_a, val_a, cursors + 0, N_NODES};
    PackArgs pe{head_e, nxt_e, inc_rows, inc_vals, sd_e, node_e, val_e, cursors + 1, N_EDGES};
    PackArgs pn{head_n, nxt_n, inc_cols, inc_vals, sd_n, edge_n, val_n, cursors + 2, N_NODES};
    pack3<<<dim3((N_EDGES + 255) / 256, 3), 256, 0, stream>>>(pa, pe, pn);
    resolve_desc<<<list_blocks, 256, 0, stream>>>(edge_n, sd_e, NNZ);
    cvt_all<<<dim3(256, 4), 256, 0, stream>>>(W00, W01, W10, W11,
                                              Wt00, Wt01, Wh10, Wl10, Wh11, Wl11);

    // 1) A = x@W00, B = x@W01 in ONE pass (B into d_out)
    mfma_gemm2<<<gemm_blocks, 256, 0, stream>>>(x, Wt00, Wt01, A_bf, B_bf, N_NODES);

    // 2) F[n] = sum v * sigmoid(D_e)  (double-CSR, resolved descriptors)
    edge_gather_csr<<<row_blocks, 256, 0, stream>>>(sd_n, edge_n, val_n,
                                                    node_e, val_e,
                                                    B_bf, F, N_NODES);

    // 3) C = sigmoid(gather_adj(A)) -> bf16  (overlays dead scratch)
    gather_csr<<<row_blocks, 256, 0, stream>>>(sd_a, col_a, val_a,
                                               A_bf, C_bf, N_NODES, 1, 1);

    // 4) E = gather_adj(C) -> fp32 in d_out (overwrites dead B region)
    gather_csr<<<row_blocks, 256, 0, stream>>>(sd_a, col_a, val_a,
                                               C_bf, E, N_NODES, 0, 0);

    // 5) out = sigmoid(E @ W10 + F @ W11)  (split-bf16 MFMA, in-place on d_out)
    final_mfma<<<final_blocks, 256, 0, stream>>>(E, F, Wh10, Wl10, Wh11, Wl11,
                                                 (float*)d_out, N_NODES);
}